// Round 10
// baseline (458.627 us; speedup 1.0000x reference)
//
#include <hip/hip_runtime.h>
#include <hip/hip_bf16.h>
#include <stdint.h>

#define NTOK   8192
#define DM     1024
#define DFF    1024
#define NEXP   64
#define TOPK   2
#define NEXPAND (NTOK*TOPK)   // 16384
#define CAP    512            // (2*N)/E

#define UNROLL _Pragma("unroll")
#define SBAR() __builtin_amdgcn_sched_barrier(0)

typedef __attribute__((ext_vector_type(4))) float f32x4;
typedef __attribute__((ext_vector_type(8))) short bf16x8;
typedef __attribute__((ext_vector_type(4))) short short4v;

__device__ __forceinline__ short f2bf(float f) {
  __hip_bfloat16 h = __float2bfloat16(f);
  union { __hip_bfloat16 h; short s; } u; u.h = h; return u.s;
}

__device__ __forceinline__ void gload16(const void* g, void* l) {
  __builtin_amdgcn_global_load_lds(
      (const __attribute__((address_space(1))) unsigned int*)g,
      (__attribute__((address_space(3))) unsigned int*)l, 16, 0, 0);
}

// ---------------- routing: exact sequential per-expert cumcount ----------------
__global__ __launch_bounds__(256) void k_route(const int* __restrict__ idx,
                                               const float* __restrict__ topw,
                                               int* __restrict__ slot_token,
                                               float* __restrict__ wslot) {
  const int ee = blockIdx.x;
  const int tid = threadIdx.x;
  const int lane = tid & 63;
  const int wv = tid >> 6;
  __shared__ int wsum[4];
  int base = 0;
  for (int it = 0; it < NEXPAND / 256; ++it) {
    int i = it * 256 + tid;
    bool m = (idx[i] == ee);
    unsigned long long bal = __ballot(m);
    int pre = __popcll(bal & ((1ull << lane) - 1ull));
    int wtot = __popcll(bal);
    if (lane == 0) wsum[wv] = wtot;
    __syncthreads();
    int wbase = 0, tot = 0;
UNROLL
    for (int w = 0; w < 4; ++w) { if (w < wv) wbase += wsum[w]; tot += wsum[w]; }
    if (m) {
      int pos = base + wbase + pre;
      if (pos < CAP) {
        slot_token[ee * CAP + pos] = i >> 1;   // token index (k=2)
        wslot[ee * CAP + pos] = topw[i];        // router weight for this slot
      }
    }
    base += tot;
    __syncthreads();
  }
  int filled = base < CAP ? base : CAP;
  for (int p = filled + tid; p < CAP; p += 256) slot_token[ee * CAP + p] = -1;
}

// ---------------- dispatch: gather + f32->bf16 ----------------
__global__ __launch_bounds__(256) void k_dispatch(const float* __restrict__ hidden,
                                                  const int* __restrict__ slot_token,
                                                  short* __restrict__ xd) {
  int row = blockIdx.x;
  int tok = slot_token[row];
  int c = threadIdx.x * 4;
  short4v v;
  if (tok >= 0) {
    float4 f = *(const float4*)(hidden + (size_t)tok * DM + c);
    v[0] = f2bf(f.x); v[1] = f2bf(f.y); v[2] = f2bf(f.z); v[3] = f2bf(f.w);
  } else {
    v[0] = 0; v[1] = 0; v[2] = 0; v[3] = 0;
  }
  *(short4v*)(xd + (size_t)row * DM + c) = v;
}

// ---------------- zero d_out (gemm2 accumulates atomically) ----------------
__global__ __launch_bounds__(256) void k_zero(float* __restrict__ out) {
  size_t i = ((size_t)blockIdx.x * 256 + threadIdx.x) * 16;
UNROLL
  for (int j = 0; j < 4; ++j) *(f32x4*)(out + i + j * 4) = (f32x4)0.f;
}

// LDS: tiles [row][32 bf16] (64B rows, 16B chunks), phys chunk = log ^ ((row>>1)&3).
// A DMA'd linear, pre-swizzled global source; B reg-staged, XOR write/read.
// Protocol: ONE s_barrier per K-step; issue order pinned (SBAR after LOADA/LOADB);
// counted vmcnt(16) drains exactly the 4 A-DMAs, leaves 16 B loads in flight.
// Geometry: 256-THREAD blocks (4 waves, 2m x 2n), wave tile 128x64, block 256x128.
// VGPR ~220 -> 8 waves/CU -> TWO blocks/CU co-resident (the R9 1-block stall fix).

// ---------------- GEMM1: act = silu(x@Wg) * (x@Wu) ----------------
// block: 256 rows x 64 act-cols (128 weight cols); wave: 128r x (32g+32u)
__global__ __launch_bounds__(256, 2) void k_gemm1(const short* __restrict__ xd,
                                                  const float* __restrict__ gup,
                                                  short* __restrict__ act) {
  __shared__ short As[2][256 * 32];
  __shared__ short Bgu[2][128 * 32];   // rows 0..63 gate cols, 64..127 up cols
  int bid0 = blockIdx.x;
  int bid = (bid0 & 7) * (2048 / 8) + (bid0 >> 3);   // XCD chunked swizzle
  const int e  = bid >> 5;
  const int mt = (bid >> 4) & 1;
  const int nt = bid & 15;
  const int tid = threadIdx.x;
  const int lane = tid & 63;
  const int wid = tid >> 6;
  const int wm = wid >> 1;   // 0..1
  const int wn = wid & 1;    // 0..1

  const short* Abase = xd + (size_t)(e * CAP + mt * 256) * DM;

  const int arowloc = wid * 16 + (lane >> 2);        // within 64-row group
  const int asw = ((lane & 3) ^ ((lane >> 3) & 3)) * 8;
  const int bcol = tid & 127;          // 0..63 gate, 64..127 up
  const int bq2 = tid >> 7;            // 0/1 -> k rows 16*bq2..+15
  const int bsw = (bcol >> 1) & 3;
  const int boff0 = bcol * 32 + (((2 * bq2)     ^ bsw) * 8);
  const int boff1 = bcol * 32 + (((2 * bq2 + 1) ^ bsw) * 8);
  const float* Wcolp = gup + (size_t)e * DM * 2048 +
                       (bcol < 64 ? nt * 64 + bcol : 960 + nt * 64 + bcol);
  const int co = (((lane >> 4) ^ ((lane >> 1) & 3))) * 8;

  f32x4 accg[8][2], accu[8][2];
UNROLL
  for (int m = 0; m < 8; ++m)
UNROLL
    for (int n = 0; n < 2; ++n) { accg[m][n] = (f32x4)0.f; accu[m][n] = (f32x4)0.f; }

  float bv_A[16], bv_B[16];

#define G1_LOADB(DST, K0)                                                      \
  { const float* p_ = Wcolp + (size_t)((K0) + 16 * bq2) * 2048;                \
UNROLL                                                                         \
    for (int j = 0; j < 16; ++j) DST[j] = p_[(size_t)j * 2048]; }

#define G1_STAGEB(BUF, SRC)                                                    \
  { bf16x8 s0_ = { f2bf(SRC[0]), f2bf(SRC[1]), f2bf(SRC[2]), f2bf(SRC[3]),     \
                   f2bf(SRC[4]), f2bf(SRC[5]), f2bf(SRC[6]), f2bf(SRC[7]) };   \
    bf16x8 s1_ = { f2bf(SRC[8]), f2bf(SRC[9]), f2bf(SRC[10]), f2bf(SRC[11]),   \
                   f2bf(SRC[12]), f2bf(SRC[13]), f2bf(SRC[14]), f2bf(SRC[15]) };\
    *(bf16x8*)&Bgu[BUF][boff0] = s0_;                                          \
    *(bf16x8*)&Bgu[BUF][boff1] = s1_; }

#define G1_LOADA(BUF, K0)                                                      \
  { gload16(Abase + (size_t)(arowloc) * DM + (K0) + asw,                       \
            &As[BUF][wid * 512]);                                              \
    gload16(Abase + (size_t)(64 + arowloc) * DM + (K0) + asw,                  \
            &As[BUF][2048 + wid * 512]);                                       \
    gload16(Abase + (size_t)(128 + arowloc) * DM + (K0) + asw,                 \
            &As[BUF][4096 + wid * 512]);                                       \
    gload16(Abase + (size_t)(192 + arowloc) * DM + (K0) + asw,                 \
            &As[BUF][6144 + wid * 512]); }

#define G1_MFMA(CUR)                                                           \
  { bf16x8 a_[8], bg_[2], bu_[2];                                              \
UNROLL                                                                         \
    for (int m = 0; m < 8; ++m)                                                \
      a_[m] = *(const bf16x8*)&As[CUR][(wm * 128 + m * 16 + (lane & 15)) * 32 + co]; \
UNROLL                                                                         \
    for (int n = 0; n < 2; ++n) {                                              \
      bg_[n] = *(const bf16x8*)&Bgu[CUR][(wn * 32 + n * 16 + (lane & 15)) * 32 + co]; \
      bu_[n] = *(const bf16x8*)&Bgu[CUR][(64 + wn * 32 + n * 16 + (lane & 15)) * 32 + co]; \
    }                                                                          \
UNROLL                                                                         \
    for (int m = 0; m < 8; ++m)                                                \
UNROLL                                                                         \
      for (int n = 0; n < 2; ++n) {                                            \
        accg[m][n] = __builtin_amdgcn_mfma_f32_16x16x32_bf16(a_[m], bg_[n], accg[m][n], 0, 0, 0); \
        accu[m][n] = __builtin_amdgcn_mfma_f32_16x16x32_bf16(a_[m], bu_[n], accu[m][n], 0, 0, 0); \
      } }

  // ---- prologue (issue order pinned: A0 DMAs oldest, then bvA, then bvB) ----
  G1_LOADA(0, 0);            SBAR();
  G1_LOADB(bv_A, 0);         SBAR();
  G1_LOADB(bv_B, 32);        SBAR();
  G1_STAGEB(0, bv_A);        // auto vmcnt(16) drains A(0)+bvA; bvB in flight
  asm volatile("s_waitcnt lgkmcnt(0)" ::: "memory");
  __builtin_amdgcn_s_barrier();
  SBAR();

#define G1_BODY(T, CUR, BR, BF, VMSTR) do {                                    \
    const int t_ = (T);                                                        \
    if (t_ < 31) G1_LOADA(CUR ^ 1, (t_ + 1) * 32);                             \
    SBAR();                                                                    \
    if (t_ < 30) G1_LOADB(BF, (t_ + 2) * 32);                                  \
    SBAR();                                                                    \
    if (t_ < 31) G1_STAGEB(CUR ^ 1, BR);                                       \
    G1_MFMA(CUR);                                                              \
    asm volatile(VMSTR ::: "memory");                                          \
    asm volatile("s_waitcnt lgkmcnt(0)" ::: "memory");                         \
    __builtin_amdgcn_s_barrier();                                              \
    SBAR();                                                                    \
  } while (0)

  for (int t2 = 0; t2 < 30; t2 += 2) {
    G1_BODY(t2,     0, bv_B, bv_A, "s_waitcnt vmcnt(16)");
    G1_BODY(t2 + 1, 1, bv_A, bv_B, "s_waitcnt vmcnt(16)");
  }
  G1_BODY(30, 0, bv_B, bv_A, "s_waitcnt vmcnt(0)");   // drain last A-DMAs
  G1_MFMA(1);                                          // t=31, no staging
#undef G1_BODY
#undef G1_LOADA
#undef G1_LOADB
#undef G1_STAGEB
#undef G1_MFMA

  // fused SwiGLU epilogue -> act bf16
  short* obase = act + (size_t)(e * CAP + mt * 256) * DFF + nt * 64;
UNROLL
  for (int m = 0; m < 8; ++m)
UNROLL
    for (int n = 0; n < 2; ++n)
UNROLL
      for (int j = 0; j < 4; ++j) {
        int rl = wm * 128 + m * 16 + (lane >> 4) * 4 + j;
        int cl = wn * 32 + n * 16 + (lane & 15);
        float g = accg[m][n][j];
        float u = accu[m][n][j];
        float s = (g / (1.f + __expf(-g))) * u;
        obase[(size_t)rl * DFF + cl] = f2bf(s);
      }
}

// ---------------- GEMM2 + fused combine: out += w * (act @ down) ----------------
// block: 256 rows x 128 cols; wave 128x64
__global__ __launch_bounds__(256, 2) void k_gemm2(const short* __restrict__ act,
                                                  const float* __restrict__ down,
                                                  const int* __restrict__ slot_token,
                                                  const float* __restrict__ wslot,
                                                  float* __restrict__ out) {
  __shared__ short As[2][256 * 32];
  __shared__ short Bt[2][128 * 32];
  int bid0 = blockIdx.x;
  int bid = (bid0 & 7) * (1024 / 8) + (bid0 >> 3);   // XCD chunked swizzle
  const int e  = bid >> 4;
  const int mt = (bid >> 3) & 1;
  const int nt = bid & 7;
  const int tid = threadIdx.x;
  const int lane = tid & 63;
  const int wid = tid >> 6;
  const int wm = wid >> 1;   // 0..1
  const int wn = wid & 1;    // 0..1

  const short* Abase = act + (size_t)(e * CAP + mt * 256) * DFF;

  const int arowloc = wid * 16 + (lane >> 2);
  const int asw = ((lane & 3) ^ ((lane >> 3) & 3)) * 8;
  const int bcol = tid & 127;
  const int bq2 = tid >> 7;
  const int bsw = (bcol >> 1) & 3;
  const int boff0 = bcol * 32 + (((2 * bq2)     ^ bsw) * 8);
  const int boff1 = bcol * 32 + (((2 * bq2 + 1) ^ bsw) * 8);
  const float* Wcolp = down + (size_t)e * DFF * DM + nt * 128 + bcol;
  const int co = (((lane >> 4) ^ ((lane >> 1) & 3))) * 8;

  f32x4 acc[8][4];
UNROLL
  for (int m = 0; m < 8; ++m)
UNROLL
    for (int n = 0; n < 4; ++n) acc[m][n] = (f32x4)0.f;

  float bv_A[16], bv_B[16];

#define G2_LOADB(DST, K0)                                                      \
  { const float* p_ = Wcolp + (size_t)((K0) + 16 * bq2) * DM;                  \
UNROLL                                                                         \
    for (int j = 0; j < 16; ++j) DST[j] = p_[(size_t)j * DM]; }

#define G2_STAGEB(BUF, SRC)                                                    \
  { bf16x8 s0_ = { f2bf(SRC[0]), f2bf(SRC[1]), f2bf(SRC[2]), f2bf(SRC[3]),     \
                   f2bf(SRC[4]), f2bf(SRC[5]), f2bf(SRC[6]), f2bf(SRC[7]) };   \
    bf16x8 s1_ = { f2bf(SRC[8]), f2bf(SRC[9]), f2bf(SRC[10]), f2bf(SRC[11]),   \
                   f2bf(SRC[12]), f2bf(SRC[13]), f2bf(SRC[14]), f2bf(SRC[15]) };\
    *(bf16x8*)&Bt[BUF][boff0] = s0_;                                           \
    *(bf16x8*)&Bt[BUF][boff1] = s1_; }

#define G2_LOADA(BUF, K0)                                                      \
  { gload16(Abase + (size_t)(arowloc) * DFF + (K0) + asw,                      \
            &As[BUF][wid * 512]);                                              \
    gload16(Abase + (size_t)(64 + arowloc) * DFF + (K0) + asw,                 \
            &As[BUF][2048 + wid * 512]);                                       \
    gload16(Abase + (size_t)(128 + arowloc) * DFF + (K0) + asw,                \
            &As[BUF][4096 + wid * 512]);                                       \
    gload16(Abase + (size_t)(192 + arowloc) * DFF + (K0) + asw,                \
            &As[BUF][6144 + wid * 512]); }

#define G2_MFMA(CUR)                                                           \
  { bf16x8 a_[8], b_[4];                                                       \
UNROLL                                                                         \
    for (int m = 0; m < 8; ++m)                                                \
      a_[m] = *(const bf16x8*)&As[CUR][(wm * 128 + m * 16 + (lane & 15)) * 32 + co]; \
UNROLL                                                                         \
    for (int n = 0; n < 4; ++n)                                                \
      b_[n] = *(const bf16x8*)&Bt[CUR][(wn * 64 + n * 16 + (lane & 15)) * 32 + co]; \
UNROLL                                                                         \
    for (int m = 0; m < 8; ++m)                                                \
UNROLL                                                                         \
      for (int n = 0; n < 4; ++n)                                              \
        acc[m][n] = __builtin_amdgcn_mfma_f32_16x16x32_bf16(a_[m], b_[n], acc[m][n], 0, 0, 0); }

  // ---- prologue (issue order pinned) ----
  G2_LOADA(0, 0);            SBAR();
  G2_LOADB(bv_A, 0);         SBAR();
  G2_LOADB(bv_B, 32);        SBAR();
  G2_STAGEB(0, bv_A);
  asm volatile("s_waitcnt lgkmcnt(0)" ::: "memory");
  __builtin_amdgcn_s_barrier();
  SBAR();

#define G2_BODY(T, CUR, BR, BF, VMSTR) do {                                    \
    const int t_ = (T);                                                        \
    if (t_ < 31) G2_LOADA(CUR ^ 1, (t_ + 1) * 32);                             \
    SBAR();                                                                    \
    if (t_ < 30) G2_LOADB(BF, (t_ + 2) * 32);                                  \
    SBAR();                                                                    \
    if (t_ < 31) G2_STAGEB(CUR ^ 1, BR);                                       \
    G2_MFMA(CUR);                                                              \
    asm volatile(VMSTR ::: "memory");                                          \
    asm volatile("s_waitcnt lgkmcnt(0)" ::: "memory");                         \
    __builtin_amdgcn_s_barrier();                                              \
    SBAR();                                                                    \
  } while (0)

  for (int t2 = 0; t2 < 30; t2 += 2) {
    G2_BODY(t2,     0, bv_B, bv_A, "s_waitcnt vmcnt(16)");
    G2_BODY(t2 + 1, 1, bv_A, bv_B, "s_waitcnt vmcnt(16)");
  }
  G2_BODY(30, 0, bv_B, bv_A, "s_waitcnt vmcnt(0)");
  G2_MFMA(1);
#undef G2_BODY
#undef G2_LOADA
#undef G2_LOADB
#undef G2_STAGEB
#undef G2_MFMA

  // fused combine epilogue: out[tok, col] += w * acc
  const int sbase = e * CAP + mt * 256;
UNROLL
  for (int m = 0; m < 8; ++m)
UNROLL
    for (int j = 0; j < 4; ++j) {
      int rl = wm * 128 + m * 16 + (lane >> 4) * 4 + j;
      int tok = slot_token[sbase + rl];
      if (tok >= 0) {
        float w = wslot[sbase + rl];
        float* orow = out + (size_t)tok * DM + nt * 128;
UNROLL
        for (int n = 0; n < 4; ++n) {
          int cl = wn * 64 + n * 16 + (lane & 15);
          atomicAdd(orow + cl, w * acc[m][n][j]);
        }
      }
    }
}

extern "C" void kernel_launch(void* const* d_in, const int* in_sizes, int n_in,
                              void* d_out, int out_size, void* d_ws, size_t ws_size,
                              hipStream_t stream) {
  const float* hidden = (const float*)d_in[0];
  const int*   idx    = (const int*)d_in[1];
  const float* topw   = (const float*)d_in[2];
  const float* gup    = (const float*)d_in[3];
  const float* down   = (const float*)d_in[4];
  float* out = (float*)d_out;

  char* ws = (char*)d_ws;
  int*   slot_token = (int*)ws;                                   // 128KB
  float* wslot      = (float*)(ws + 131072);                      // 128KB
  short* xd  = (short*)(ws + 262144);                             // 64MB bf16
  short* act = xd + (size_t)NEXP * CAP * DM;                      // 64MB bf16

  k_route<<<NEXP, 256, 0, stream>>>(idx, topw, slot_token, wslot);
  k_dispatch<<<NEXP * CAP, 256, 0, stream>>>(hidden, slot_token, xd);
  k_zero<<<2048, 256, 0, stream>>>(out);
  k_gemm1<<<2048, 256, 0, stream>>>(xd, gup, act);
  k_gemm2<<<1024, 256, 0, stream>>>(act, down, slot_token, wslot, out);
}

// Round 11
// 426.146 us; speedup vs baseline: 1.0762x; 1.0762x over previous
//
#include <hip/hip_runtime.h>
#include <hip/hip_bf16.h>
#include <stdint.h>

#define NTOK   8192
#define DM     1024
#define DFF    1024
#define NEXP   64
#define TOPK   2
#define NEXPAND (NTOK*TOPK)   // 16384
#define CAP    512            // (2*N)/E

#define UNROLL _Pragma("unroll")
#define SBAR() __builtin_amdgcn_sched_barrier(0)

typedef __attribute__((ext_vector_type(4))) float f32x4;
typedef __attribute__((ext_vector_type(8))) short bf16x8;
typedef __attribute__((ext_vector_type(4))) short short4v;

__device__ __forceinline__ short f2bf(float f) {
  __hip_bfloat16 h = __float2bfloat16(f);
  union { __hip_bfloat16 h; short s; } u; u.h = h; return u.s;
}

__device__ __forceinline__ void gload16(const void* g, void* l) {
  __builtin_amdgcn_global_load_lds(
      (const __attribute__((address_space(1))) unsigned int*)g,
      (__attribute__((address_space(3))) unsigned int*)l, 16, 0, 0);
}

// ---------------- routing: exact sequential per-expert cumcount ----------------
__global__ __launch_bounds__(256) void k_route(const int* __restrict__ idx,
                                               const float* __restrict__ topw,
                                               int* __restrict__ slot_token,
                                               float* __restrict__ wslot) {
  const int ee = blockIdx.x;
  const int tid = threadIdx.x;
  const int lane = tid & 63;
  const int wv = tid >> 6;
  __shared__ int wsum[4];
  int base = 0;
  for (int it = 0; it < NEXPAND / 256; ++it) {
    int i = it * 256 + tid;
    bool m = (idx[i] == ee);
    unsigned long long bal = __ballot(m);
    int pre = __popcll(bal & ((1ull << lane) - 1ull));
    int wtot = __popcll(bal);
    if (lane == 0) wsum[wv] = wtot;
    __syncthreads();
    int wbase = 0, tot = 0;
UNROLL
    for (int w = 0; w < 4; ++w) { if (w < wv) wbase += wsum[w]; tot += wsum[w]; }
    if (m) {
      int pos = base + wbase + pre;
      if (pos < CAP) {
        slot_token[ee * CAP + pos] = i >> 1;   // token index (k=2)
        wslot[ee * CAP + pos] = topw[i];        // router weight for this slot
      }
    }
    base += tot;
    __syncthreads();
  }
  int filled = base < CAP ? base : CAP;
  for (int p = filled + tid; p < CAP; p += 256) slot_token[ee * CAP + p] = -1;
}

// ---------------- dispatch: gather + f32->bf16 ----------------
__global__ __launch_bounds__(256) void k_dispatch(const float* __restrict__ hidden,
                                                  const int* __restrict__ slot_token,
                                                  short* __restrict__ xd) {
  int row = blockIdx.x;
  int tok = slot_token[row];
  int c = threadIdx.x * 4;
  short4v v;
  if (tok >= 0) {
    float4 f = *(const float4*)(hidden + (size_t)tok * DM + c);
    v[0] = f2bf(f.x); v[1] = f2bf(f.y); v[2] = f2bf(f.z); v[3] = f2bf(f.w);
  } else {
    v[0] = 0; v[1] = 0; v[2] = 0; v[3] = 0;
  }
  *(short4v*)(xd + (size_t)row * DM + c) = v;
}

// ---------------- zero d_out (gemm2 accumulates atomically) ----------------
__global__ __launch_bounds__(256) void k_zero(float* __restrict__ out) {
  size_t i = ((size_t)blockIdx.x * 256 + threadIdx.x) * 16;
UNROLL
  for (int j = 0; j < 4; ++j) *(f32x4*)(out + i + j * 4) = (f32x4)0.f;
}

// R6-exact GEMM structure (the 397-us measured optimum):
// LDS tiles [row][32 bf16] (64B rows, 16B chunks), phys chunk = log ^ ((row>>1)&3).
// A DMA'd linear (pre-swizzled global source); B reg-staged, XOR write/read.
// ONE s_barrier per K-step, counted vmcnt(8) (drains 2 A-DMAs, leaves 8 B loads
// in flight a full K-step). Peeled tail (vmcnt(0) at t=30) fixes R6's latent race.

// ---------------- GEMM1: act = silu(x@Wg) * (x@Wu) ----------------
// block 256 rows x (64 gate + 64 up), 8 waves, wave tile 64r x (32g+32u)
__global__ __launch_bounds__(512, 4) void k_gemm1(const short* __restrict__ xd,
                                                  const float* __restrict__ gup,
                                                  short* __restrict__ act) {
  __shared__ short As[2][256 * 32];
  __shared__ short Bg[2][64 * 32];
  __shared__ short Bu[2][64 * 32];
  int bid0 = blockIdx.x;
  int bid = (bid0 & 7) * (2048 / 8) + (bid0 >> 3);   // XCD chunked swizzle
  const int e  = bid >> 5;
  const int mt = (bid >> 4) & 1;
  const int nt = bid & 15;
  const int tid = threadIdx.x;
  const int lane = tid & 63;
  const int wid = tid >> 6;
  const int wm = wid >> 1;   // 0..3
  const int wn = wid & 1;    // 0..1

  const short* Abase = xd + (size_t)(e * CAP + mt * 256) * DM;
  const float* Wg = gup + (size_t)e * DM * 2048 + nt * 64;

  const int arowloc = wid * 16 + (lane >> 2);
  const int asw = ((lane & 3) ^ ((lane >> 3) & 3)) * 8;   // pre-swizzled src chunk
  const int bn = tid & 63;          // column 0..63
  const int bq = tid >> 6;          // 0..7 -> rows 4bq..4bq+3
  const int boff = bn * 32 + (((bq >> 1) ^ ((bn >> 1) & 3)) * 8) + 4 * (bq & 1);
  const int co = (((lane >> 4) ^ ((lane >> 1) & 3))) * 8;

  f32x4 accg[4][2], accu[4][2];
UNROLL
  for (int m = 0; m < 4; ++m)
UNROLL
    for (int n = 0; n < 2; ++n) { accg[m][n] = (f32x4)0.f; accu[m][n] = (f32x4)0.f; }

  float gvA[4], uvA[4], gvB[4], uvB[4];

  // ---- prologue: A(0) DMA; B(0)->bvA; B(1)->bvB; stage B(0); barrier ----
  gload16(Abase + (size_t)(arowloc) * DM + asw, &As[0][wid * 512]);
  gload16(Abase + (size_t)(128 + arowloc) * DM + asw, &As[0][4096 + wid * 512]);
  {
    const float* gp = Wg + (size_t)(4 * bq) * 2048 + bn;
UNROLL
    for (int j = 0; j < 4; ++j) { gvA[j] = gp[(size_t)j * 2048]; uvA[j] = gp[(size_t)j * 2048 + 1024]; }
  }
  {
    const float* gp = Wg + (size_t)(32 + 4 * bq) * 2048 + bn;
UNROLL
    for (int j = 0; j < 4; ++j) { gvB[j] = gp[(size_t)j * 2048]; uvB[j] = gp[(size_t)j * 2048 + 1024]; }
  }
  {
    // auto-wait here drains A(0) (older) + bvA; bvB stays in flight
    short4v sg = { f2bf(gvA[0]), f2bf(gvA[1]), f2bf(gvA[2]), f2bf(gvA[3]) };
    short4v su = { f2bf(uvA[0]), f2bf(uvA[1]), f2bf(uvA[2]), f2bf(uvA[3]) };
    *(short4v*)&Bg[0][boff] = sg;
    *(short4v*)&Bu[0][boff] = su;
  }
  asm volatile("s_waitcnt lgkmcnt(0)" ::: "memory");
  __builtin_amdgcn_s_barrier();
  SBAR();

#define G1_BODY(T, CUR, GR, UR, GF, UF, VMSTR) do {                            \
    const int t_ = (T);                                                        \
    if (t_ < 31) {                                                             \
      const int k0_ = (t_ + 1) * 32;                                           \
      gload16(Abase + (size_t)(arowloc) * DM + k0_ + asw,                      \
              &As[(CUR) ^ 1][wid * 512]);                                      \
      gload16(Abase + (size_t)(128 + arowloc) * DM + k0_ + asw,                \
              &As[(CUR) ^ 1][4096 + wid * 512]);                               \
    }                                                                          \
    if (t_ < 30) {                                                             \
      const float* gp_ = Wg + (size_t)((t_ + 2) * 32 + 4 * bq) * 2048 + bn;    \
      GF[0] = gp_[0];    GF[1] = gp_[2048]; GF[2] = gp_[4096]; GF[3] = gp_[6144]; \
      UF[0] = gp_[1024]; UF[1] = gp_[3072]; UF[2] = gp_[5120]; UF[3] = gp_[7168]; \
    }                                                                          \
    if (t_ < 31) {                                                             \
      short4v sg_ = { f2bf(GR[0]), f2bf(GR[1]), f2bf(GR[2]), f2bf(GR[3]) };    \
      short4v su_ = { f2bf(UR[0]), f2bf(UR[1]), f2bf(UR[2]), f2bf(UR[3]) };    \
      *(short4v*)&Bg[(CUR) ^ 1][boff] = sg_;                                   \
      *(short4v*)&Bu[(CUR) ^ 1][boff] = su_;                                   \
    }                                                                          \
    {                                                                          \
      bf16x8 a_[4], bg_[2], bu_[2];                                            \
UNROLL                                                                         \
      for (int m = 0; m < 4; ++m)                                              \
        a_[m] = *(const bf16x8*)&As[CUR][(wm * 64 + m * 16 + (lane & 15)) * 32 + co]; \
UNROLL                                                                         \
      for (int n = 0; n < 2; ++n) {                                            \
        bg_[n] = *(const bf16x8*)&Bg[CUR][(wn * 32 + n * 16 + (lane & 15)) * 32 + co]; \
        bu_[n] = *(const bf16x8*)&Bu[CUR][(wn * 32 + n * 16 + (lane & 15)) * 32 + co]; \
      }                                                                        \
UNROLL                                                                         \
      for (int m = 0; m < 4; ++m)                                              \
UNROLL                                                                         \
        for (int n = 0; n < 2; ++n) {                                          \
          accg[m][n] = __builtin_amdgcn_mfma_f32_16x16x32_bf16(a_[m], bg_[n], accg[m][n], 0, 0, 0); \
          accu[m][n] = __builtin_amdgcn_mfma_f32_16x16x32_bf16(a_[m], bu_[n], accu[m][n], 0, 0, 0); \
        }                                                                      \
    }                                                                          \
    asm volatile(VMSTR ::: "memory");                                          \
    asm volatile("s_waitcnt lgkmcnt(0)" ::: "memory");                         \
    __builtin_amdgcn_s_barrier();                                              \
    SBAR();                                                                    \
  } while (0)

  for (int t2 = 0; t2 < 30; t2 += 2) {
    G1_BODY(t2,     0, gvB, uvB, gvA, uvA, "s_waitcnt vmcnt(8)");
    G1_BODY(t2 + 1, 1, gvA, uvA, gvB, uvB, "s_waitcnt vmcnt(8)");
  }
  G1_BODY(30, 0, gvB, uvB, gvA, uvA, "s_waitcnt vmcnt(0)");  // drain last A-DMA
  G1_BODY(31, 1, gvA, uvA, gvB, uvB, "s_waitcnt vmcnt(0)");  // pure MFMA (guards skip staging)
#undef G1_BODY

  // fused SwiGLU epilogue -> act bf16
  short* obase = act + (size_t)(e * CAP + mt * 256) * DFF + nt * 64;
UNROLL
  for (int m = 0; m < 4; ++m)
UNROLL
    for (int n = 0; n < 2; ++n)
UNROLL
      for (int j = 0; j < 4; ++j) {
        int rl = wm * 64 + m * 16 + (lane >> 4) * 4 + j;
        int cl = wn * 32 + n * 16 + (lane & 15);
        float g = accg[m][n][j];
        float u = accu[m][n][j];
        float s = (g / (1.f + __expf(-g))) * u;
        obase[(size_t)rl * DFF + cl] = f2bf(s);
      }
}

// ---------------- GEMM2 + fused combine: out += w * (act @ down) ----------------
// block 256 rows x 128 cols, 8 waves, wave tile 64x64
__global__ __launch_bounds__(512, 4) void k_gemm2(const short* __restrict__ act,
                                                  const float* __restrict__ down,
                                                  const int* __restrict__ slot_token,
                                                  const float* __restrict__ wslot,
                                                  float* __restrict__ out) {
  __shared__ short As[2][256 * 32];
  __shared__ short Bt[2][128 * 32];
  int bid0 = blockIdx.x;
  int bid = (bid0 & 7) * (1024 / 8) + (bid0 >> 3);   // XCD chunked swizzle
  const int e  = bid >> 4;
  const int mt = (bid >> 3) & 1;
  const int nt = bid & 7;
  const int tid = threadIdx.x;
  const int lane = tid & 63;
  const int wid = tid >> 6;
  const int wm = wid >> 1;   // 0..3
  const int wn = wid & 1;    // 0..1

  const short* Abase = act + (size_t)(e * CAP + mt * 256) * DFF;
  const float* Wb = down + (size_t)e * DFF * DM + nt * 128;

  const int arowloc = wid * 16 + (lane >> 2);
  const int asw = ((lane & 3) ^ ((lane >> 3) & 3)) * 8;
  const int bn = tid & 127;         // column 0..127
  const int bq = tid >> 7;          // 0..3 -> rows 8bq..8bq+7
  const int boff = bn * 32 + ((bq ^ ((bn >> 1) & 3)) * 8);
  const int co = (((lane >> 4) ^ ((lane >> 1) & 3))) * 8;

  f32x4 acc[4][4];
UNROLL
  for (int m = 0; m < 4; ++m)
UNROLL
    for (int n = 0; n < 4; ++n) acc[m][n] = (f32x4)0.f;

  float bvA[8], bvB[8];

  // ---- prologue ----
  gload16(Abase + (size_t)(arowloc) * DFF + asw, &As[0][wid * 512]);
  gload16(Abase + (size_t)(128 + arowloc) * DFF + asw, &As[0][4096 + wid * 512]);
  {
    const float* bp = Wb + (size_t)(8 * bq) * DM + bn;
UNROLL
    for (int j = 0; j < 8; ++j) bvA[j] = bp[(size_t)j * DM];
  }
  {
    const float* bp = Wb + (size_t)(32 + 8 * bq) * DM + bn;
UNROLL
    for (int j = 0; j < 8; ++j) bvB[j] = bp[(size_t)j * DM];
  }
  {
    bf16x8 sb = { f2bf(bvA[0]), f2bf(bvA[1]), f2bf(bvA[2]), f2bf(bvA[3]),
                  f2bf(bvA[4]), f2bf(bvA[5]), f2bf(bvA[6]), f2bf(bvA[7]) };
    *(bf16x8*)&Bt[0][boff] = sb;
  }
  asm volatile("s_waitcnt lgkmcnt(0)" ::: "memory");
  __builtin_amdgcn_s_barrier();
  SBAR();

#define G2_BODY(T, CUR, BR, BF, VMSTR) do {                                    \
    const int t_ = (T);                                                        \
    if (t_ < 31) {                                                             \
      const int k0_ = (t_ + 1) * 32;                                           \
      gload16(Abase + (size_t)(arowloc) * DFF + k0_ + asw,                     \
              &As[(CUR) ^ 1][wid * 512]);                                      \
      gload16(Abase + (size_t)(128 + arowloc) * DFF + k0_ + asw,               \
              &As[(CUR) ^ 1][4096 + wid * 512]);                               \
    }                                                                          \
    if (t_ < 30) {                                                             \
      const float* bp_ = Wb + (size_t)((t_ + 2) * 32 + 8 * bq) * DM + bn;      \
      BF[0] = bp_[0];        BF[1] = bp_[DM];     BF[2] = bp_[2 * DM];         \
      BF[3] = bp_[3 * DM];   BF[4] = bp_[4 * DM]; BF[5] = bp_[5 * DM];         \
      BF[6] = bp_[6 * DM];   BF[7] = bp_[7 * DM];                              \
    }                                                                          \
    if (t_ < 31) {                                                             \
      bf16x8 sb_ = { f2bf(BR[0]), f2bf(BR[1]), f2bf(BR[2]), f2bf(BR[3]),       \
                     f2bf(BR[4]), f2bf(BR[5]), f2bf(BR[6]), f2bf(BR[7]) };     \
      *(bf16x8*)&Bt[(CUR) ^ 1][boff] = sb_;                                    \
    }                                                                          \
    {                                                                          \
      bf16x8 a_[4], b_[4];                                                     \
UNROLL                                                                         \
      for (int m = 0; m < 4; ++m)                                              \
        a_[m] = *(const bf16x8*)&As[CUR][(wm * 64 + m * 16 + (lane & 15)) * 32 + co]; \
UNROLL                                                                         \
      for (int n = 0; n < 4; ++n)                                              \
        b_[n] = *(const bf16x8*)&Bt[CUR][(wn * 64 + n * 16 + (lane & 15)) * 32 + co]; \
UNROLL                                                                         \
      for (int m = 0; m < 4; ++m)                                              \
UNROLL                                                                         \
        for (int n = 0; n < 4; ++n)                                            \
          acc[m][n] = __builtin_amdgcn_mfma_f32_16x16x32_bf16(a_[m], b_[n], acc[m][n], 0, 0, 0); \
    }                                                                          \
    asm volatile(VMSTR ::: "memory");                                          \
    asm volatile("s_waitcnt lgkmcnt(0)" ::: "memory");                         \
    __builtin_amdgcn_s_barrier();                                              \
    SBAR();                                                                    \
  } while (0)

  for (int t2 = 0; t2 < 30; t2 += 2) {
    G2_BODY(t2,     0, bvB, bvA, "s_waitcnt vmcnt(8)");
    G2_BODY(t2 + 1, 1, bvA, bvB, "s_waitcnt vmcnt(8)");
  }
  G2_BODY(30, 0, bvB, bvA, "s_waitcnt vmcnt(0)");  // drain last A-DMA
  G2_BODY(31, 1, bvA, bvB, "s_waitcnt vmcnt(0)");  // pure MFMA
#undef G2_BODY

  // fused combine epilogue: out[tok, col] += w * acc
  const int sbase = e * CAP + mt * 256;
UNROLL
  for (int m = 0; m < 4; ++m)
UNROLL
    for (int j = 0; j < 4; ++j) {
      int rl = wm * 64 + m * 16 + (lane >> 4) * 4 + j;
      int tok = slot_token[sbase + rl];
      if (tok >= 0) {
        float w = wslot[sbase + rl];
        float* orow = out + (size_t)tok * DM + nt * 128;
UNROLL
        for (int n = 0; n < 4; ++n) {
          int cl = wn * 64 + n * 16 + (lane & 15);
          atomicAdd(orow + cl, w * acc[m][n][j]);
        }
      }
    }
}

extern "C" void kernel_launch(void* const* d_in, const int* in_sizes, int n_in,
                              void* d_out, int out_size, void* d_ws, size_t ws_size,
                              hipStream_t stream) {
  const float* hidden = (const float*)d_in[0];
  const int*   idx    = (const int*)d_in[1];
  const float* topw   = (const float*)d_in[2];
  const float* gup    = (const float*)d_in[3];
  const float* down   = (const float*)d_in[4];
  float* out = (float*)d_out;

  char* ws = (char*)d_ws;
  int*   slot_token = (int*)ws;                                   // 128KB
  float* wslot      = (float*)(ws + 131072);                      // 128KB
  short* xd  = (short*)(ws + 262144);                             // 64MB bf16
  short* act = xd + (size_t)NEXP * CAP * DM;                      // 64MB bf16

  k_route<<<NEXP, 256, 0, stream>>>(idx, topw, slot_token, wslot);
  k_dispatch<<<NEXP * CAP, 256, 0, stream>>>(hidden, slot_token, xd);
  k_zero<<<2048, 256, 0, stream>>>(out);
  k_gemm1<<<2048, 512, 0, stream>>>(xd, gup, act);
  k_gemm2<<<1024, 512, 0, stream>>>(act, down, slot_token, wslot, out);
}

// Round 12
// 400.904 us; speedup vs baseline: 1.1440x; 1.0630x over previous
//
#include <hip/hip_runtime.h>
#include <hip/hip_bf16.h>
#include <stdint.h>

#define NTOK   8192
#define DM     1024
#define DFF    1024
#define NEXP   64
#define TOPK   2
#define NEXPAND (NTOK*TOPK)   // 16384
#define CAP    512            // (2*N)/E

#define UNROLL _Pragma("unroll")
#define SBAR() __builtin_amdgcn_sched_barrier(0)

typedef __attribute__((ext_vector_type(4))) float f32x4;
typedef __attribute__((ext_vector_type(8))) short bf16x8;
typedef __attribute__((ext_vector_type(4))) short short4v;

__device__ __forceinline__ short f2bf(float f) {
  __hip_bfloat16 h = __float2bfloat16(f);
  union { __hip_bfloat16 h; short s; } u; u.h = h; return u.s;
}
__device__ __forceinline__ float bf2f(short s) {
  union { float f; uint32_t u; } u; u.u = ((uint32_t)(uint16_t)s) << 16; return u.f;
}

__device__ __forceinline__ void gload16(const void* g, void* l) {
  __builtin_amdgcn_global_load_lds(
      (const __attribute__((address_space(1))) unsigned int*)g,
      (__attribute__((address_space(3))) unsigned int*)l, 16, 0, 0);
}

// ---------------- routing: exact sequential per-expert cumcount ----------------
__global__ __launch_bounds__(256) void k_route(const int* __restrict__ idx,
                                               int* __restrict__ slot_token,
                                               int* __restrict__ comb_slot) {
  const int ee = blockIdx.x;
  const int tid = threadIdx.x;
  const int lane = tid & 63;
  const int wv = tid >> 6;
  __shared__ int wsum[4];
  int base = 0;
  for (int it = 0; it < NEXPAND / 256; ++it) {
    int i = it * 256 + tid;
    bool m = (idx[i] == ee);
    unsigned long long bal = __ballot(m);
    int pre = __popcll(bal & ((1ull << lane) - 1ull));
    int wtot = __popcll(bal);
    if (lane == 0) wsum[wv] = wtot;
    __syncthreads();
    int wbase = 0, tot = 0;
UNROLL
    for (int w = 0; w < 4; ++w) { if (w < wv) wbase += wsum[w]; tot += wsum[w]; }
    if (m) {
      int pos = base + wbase + pre;
      if (pos < CAP) {
        comb_slot[i] = ee * CAP + pos;
        slot_token[ee * CAP + pos] = i >> 1;   // token index (k=2)
      } else {
        comb_slot[i] = -1;                      // dropped over capacity
      }
    }
    base += tot;
    __syncthreads();
  }
  int filled = base < CAP ? base : CAP;
  for (int p = filled + tid; p < CAP; p += 256) slot_token[ee * CAP + p] = -1;
}

// ---------------- dispatch: gather + f32->bf16 ----------------
__global__ __launch_bounds__(256) void k_dispatch(const float* __restrict__ hidden,
                                                  const int* __restrict__ slot_token,
                                                  short* __restrict__ xd) {
  int row = blockIdx.x;
  int tok = slot_token[row];
  int c = threadIdx.x * 4;
  short4v v;
  if (tok >= 0) {
    float4 f = *(const float4*)(hidden + (size_t)tok * DM + c);
    v[0] = f2bf(f.x); v[1] = f2bf(f.y); v[2] = f2bf(f.z); v[3] = f2bf(f.w);
  } else {
    v[0] = 0; v[1] = 0; v[2] = 0; v[3] = 0;
  }
  *(short4v*)(xd + (size_t)row * DM + c) = v;
}

// LDS tiles [row][32 bf16] (64B rows, 16B chunks), phys chunk = log ^ ((row>>1)&3).
// A DMA'd linear (pre-swizzled global source); B reg-staged, XOR write/read.
// DEPTH-2 A PIPELINE: 3 LDS A-buffers; body t issues A(t+2)/B(t+2), MFMA(t),
// then vmcnt(10) drains A(t+1)+bv(t+1) (issued a FULL BODY earlier -> ~400cy
// cover vs R6's ~150cy), stages B(t+1), lgkm, barrier. Issue order pinned.

// ---------------- GEMM1: act = silu(x@Wg) * (x@Wu) ----------------
// block 256 rows x (64 gate + 64 up), 8 waves, wave tile 64r x (32g+32u)
__global__ __launch_bounds__(512, 4) void k_gemm1(const short* __restrict__ xd,
                                                  const float* __restrict__ gup,
                                                  short* __restrict__ act) {
  __shared__ short As[3][256 * 32];
  __shared__ short Bg[2][64 * 32];
  __shared__ short Bu[2][64 * 32];
  int bid0 = blockIdx.x;
  int bid = (bid0 & 7) * (2048 / 8) + (bid0 >> 3);   // XCD chunked swizzle
  const int e  = bid >> 5;
  const int mt = (bid >> 4) & 1;
  const int nt = bid & 15;
  const int tid = threadIdx.x;
  const int lane = tid & 63;
  const int wid = tid >> 6;
  const int wm = wid >> 1;   // 0..3
  const int wn = wid & 1;    // 0..1

  const short* Abase = xd + (size_t)(e * CAP + mt * 256) * DM;
  const float* Wg = gup + (size_t)e * DM * 2048 + nt * 64;

  const int arowloc = wid * 16 + (lane >> 2);
  const int asw = ((lane & 3) ^ ((lane >> 3) & 3)) * 8;
  const int bn = tid & 63;          // column 0..63
  const int bq = tid >> 6;          // 0..7 -> rows 4bq..4bq+3
  const int boff = bn * 32 + (((bq >> 1) ^ ((bn >> 1) & 3)) * 8) + 4 * (bq & 1);
  const int co = (((lane >> 4) ^ ((lane >> 1) & 3))) * 8;

  f32x4 accg[4][2], accu[4][2];
UNROLL
  for (int m = 0; m < 4; ++m)
UNROLL
    for (int n = 0; n < 2; ++n) { accg[m][n] = (f32x4)0.f; accu[m][n] = (f32x4)0.f; }

  float gv0[4], uv0[4], gv1[4], uv1[4];

#define G1_LOADA(BUF, K0)                                                      \
  { gload16(Abase + (size_t)(arowloc) * DM + (K0) + asw, &As[BUF][wid * 512]); \
    gload16(Abase + (size_t)(128 + arowloc) * DM + (K0) + asw,                 \
            &As[BUF][4096 + wid * 512]); }

#define G1_LOADB(GD, UD, K0)                                                   \
  { const float* gp_ = Wg + (size_t)((K0) + 4 * bq) * 2048 + bn;               \
    GD[0] = gp_[0];    GD[1] = gp_[2048]; GD[2] = gp_[4096]; GD[3] = gp_[6144];\
    UD[0] = gp_[1024]; UD[1] = gp_[3072]; UD[2] = gp_[5120]; UD[3] = gp_[7168]; }

#define G1_STAGEB(BUF, GR, UR)                                                 \
  { short4v sg_ = { f2bf(GR[0]), f2bf(GR[1]), f2bf(GR[2]), f2bf(GR[3]) };      \
    short4v su_ = { f2bf(UR[0]), f2bf(UR[1]), f2bf(UR[2]), f2bf(UR[3]) };      \
    *(short4v*)&Bg[BUF][boff] = sg_;                                           \
    *(short4v*)&Bu[BUF][boff] = su_; }

#define G1_MFMA(AR, BR)                                                        \
  { bf16x8 a_[4], bg_[2], bu_[2];                                              \
UNROLL                                                                         \
    for (int m = 0; m < 4; ++m)                                                \
      a_[m] = *(const bf16x8*)&As[AR][(wm * 64 + m * 16 + (lane & 15)) * 32 + co]; \
UNROLL                                                                         \
    for (int n = 0; n < 2; ++n) {                                              \
      bg_[n] = *(const bf16x8*)&Bg[BR][(wn * 32 + n * 16 + (lane & 15)) * 32 + co]; \
      bu_[n] = *(const bf16x8*)&Bu[BR][(wn * 32 + n * 16 + (lane & 15)) * 32 + co]; \
    }                                                                          \
UNROLL                                                                         \
    for (int m = 0; m < 4; ++m)                                                \
UNROLL                                                                         \
      for (int n = 0; n < 2; ++n) {                                            \
        accg[m][n] = __builtin_amdgcn_mfma_f32_16x16x32_bf16(a_[m], bg_[n], accg[m][n], 0, 0, 0); \
        accu[m][n] = __builtin_amdgcn_mfma_f32_16x16x32_bf16(a_[m], bu_[n], accu[m][n], 0, 0, 0); \
      } }

  // ---- prologue: A0->As0, A1->As1, bv0, bv1; stage B0; barrier ----
  G1_LOADA(0, 0);    SBAR();
  G1_LOADA(1, 32);   SBAR();
  G1_LOADB(gv0, uv0, 0);   SBAR();
  G1_LOADB(gv1, uv1, 32);  SBAR();
  asm volatile("s_waitcnt vmcnt(8)" ::: "memory");   // drain A0,A1,bv0; bv1 in flight
  G1_STAGEB(0, gv0, uv0);
  asm volatile("s_waitcnt lgkmcnt(0)" ::: "memory");
  __builtin_amdgcn_s_barrier();
  SBAR();

// body T (0..29): issue A(T+2)->As[(T+2)%3], B(T+2)->reg[T&1]; MFMA(T);
// vmcnt(10) drains A(T+1)+bv(T+1); stage B(T+1) from reg[(T+1)&1]; barrier.
#define G1_BODY(T, ARD, AWR, BRD, BWR, GR, UR, GW, UW) do {                    \
    G1_LOADA(AWR, ((T) + 2) * 32);           SBAR();                           \
    G1_LOADB(GW, UW, ((T) + 2) * 32);        SBAR();                           \
    G1_MFMA(ARD, BRD);                                                         \
    asm volatile("s_waitcnt vmcnt(10)" ::: "memory");                          \
    G1_STAGEB(BWR, GR, UR);                                                    \
    asm volatile("s_waitcnt lgkmcnt(0)" ::: "memory");                         \
    __builtin_amdgcn_s_barrier();                                              \
    SBAR();                                                                    \
  } while (0)

  for (int t6 = 0; t6 < 30; t6 += 6) {
    G1_BODY(t6,     0, 2, 0, 1, gv1, uv1, gv0, uv0);
    G1_BODY(t6 + 1, 1, 0, 1, 0, gv0, uv0, gv1, uv1);
    G1_BODY(t6 + 2, 2, 1, 0, 1, gv1, uv1, gv0, uv0);
    G1_BODY(t6 + 3, 0, 2, 1, 0, gv0, uv0, gv1, uv1);
    G1_BODY(t6 + 4, 1, 0, 0, 1, gv1, uv1, gv0, uv0);
    G1_BODY(t6 + 5, 2, 1, 1, 0, gv0, uv0, gv1, uv1);
  }
  // t=30: no issues; MFMA(30) As0,B0; vmcnt(0) drains bv(31); stage B(31)->B1
  G1_MFMA(0, 0);
  asm volatile("s_waitcnt vmcnt(0)" ::: "memory");
  G1_STAGEB(1, gv1, uv1);
  asm volatile("s_waitcnt lgkmcnt(0)" ::: "memory");
  __builtin_amdgcn_s_barrier();
  SBAR();
  // t=31: MFMA only
  G1_MFMA(1, 1);
#undef G1_BODY
#undef G1_LOADA
#undef G1_LOADB
#undef G1_STAGEB
#undef G1_MFMA

  // fused SwiGLU epilogue -> act bf16
  short* obase = act + (size_t)(e * CAP + mt * 256) * DFF + nt * 64;
UNROLL
  for (int m = 0; m < 4; ++m)
UNROLL
    for (int n = 0; n < 2; ++n)
UNROLL
      for (int j = 0; j < 4; ++j) {
        int rl = wm * 64 + m * 16 + (lane >> 4) * 4 + j;
        int cl = wn * 32 + n * 16 + (lane & 15);
        float g = accg[m][n][j];
        float u = accu[m][n][j];
        float s = (g / (1.f + __expf(-g))) * u;
        obase[(size_t)rl * DFF + cl] = f2bf(s);
      }
}

// ---------------- GEMM2: yd = act @ down (yd bf16) ----------------
// block 256 rows x 128 cols, 8 waves, wave tile 64x64
__global__ __launch_bounds__(512, 4) void k_gemm2(const short* __restrict__ act,
                                                  const float* __restrict__ down,
                                                  short* __restrict__ yd) {
  __shared__ short As[3][256 * 32];
  __shared__ short Bt[2][128 * 32];
  int bid0 = blockIdx.x;
  int bid = (bid0 & 7) * (1024 / 8) + (bid0 >> 3);   // XCD chunked swizzle
  const int e  = bid >> 4;
  const int mt = (bid >> 3) & 1;
  const int nt = bid & 7;
  const int tid = threadIdx.x;
  const int lane = tid & 63;
  const int wid = tid >> 6;
  const int wm = wid >> 1;   // 0..3
  const int wn = wid & 1;    // 0..1

  const short* Abase = act + (size_t)(e * CAP + mt * 256) * DFF;
  const float* Wb = down + (size_t)e * DFF * DM + nt * 128;

  const int arowloc = wid * 16 + (lane >> 2);
  const int asw = ((lane & 3) ^ ((lane >> 3) & 3)) * 8;
  const int bn = tid & 127;         // column 0..127
  const int bq = tid >> 7;          // 0..3 -> rows 8bq..8bq+7
  const int boff = bn * 32 + ((bq ^ ((bn >> 1) & 3)) * 8);
  const int co = (((lane >> 4) ^ ((lane >> 1) & 3))) * 8;

  f32x4 acc[4][4];
UNROLL
  for (int m = 0; m < 4; ++m)
UNROLL
    for (int n = 0; n < 4; ++n) acc[m][n] = (f32x4)0.f;

  float bv0[8], bv1[8];

#define G2_LOADA(BUF, K0)                                                      \
  { gload16(Abase + (size_t)(arowloc) * DFF + (K0) + asw, &As[BUF][wid * 512]);\
    gload16(Abase + (size_t)(128 + arowloc) * DFF + (K0) + asw,                \
            &As[BUF][4096 + wid * 512]); }

#define G2_LOADB(DST, K0)                                                      \
  { const float* bp_ = Wb + (size_t)((K0) + 8 * bq) * DM + bn;                 \
    DST[0] = bp_[0];        DST[1] = bp_[DM];     DST[2] = bp_[2 * DM];        \
    DST[3] = bp_[3 * DM];   DST[4] = bp_[4 * DM]; DST[5] = bp_[5 * DM];        \
    DST[6] = bp_[6 * DM];   DST[7] = bp_[7 * DM]; }

#define G2_STAGEB(BUF, SRC)                                                    \
  { bf16x8 sb_ = { f2bf(SRC[0]), f2bf(SRC[1]), f2bf(SRC[2]), f2bf(SRC[3]),     \
                   f2bf(SRC[4]), f2bf(SRC[5]), f2bf(SRC[6]), f2bf(SRC[7]) };   \
    *(bf16x8*)&Bt[BUF][boff] = sb_; }

#define G2_MFMA(AR, BR)                                                        \
  { bf16x8 a_[4], b_[4];                                                       \
UNROLL                                                                         \
    for (int m = 0; m < 4; ++m)                                                \
      a_[m] = *(const bf16x8*)&As[AR][(wm * 64 + m * 16 + (lane & 15)) * 32 + co]; \
UNROLL                                                                         \
    for (int n = 0; n < 4; ++n)                                                \
      b_[n] = *(const bf16x8*)&Bt[BR][(wn * 64 + n * 16 + (lane & 15)) * 32 + co]; \
UNROLL                                                                         \
    for (int m = 0; m < 4; ++m)                                                \
UNROLL                                                                         \
      for (int n = 0; n < 4; ++n)                                              \
        acc[m][n] = __builtin_amdgcn_mfma_f32_16x16x32_bf16(a_[m], b_[n], acc[m][n], 0, 0, 0); }

  // ---- prologue ----
  G2_LOADA(0, 0);    SBAR();
  G2_LOADA(1, 32);   SBAR();
  G2_LOADB(bv0, 0);  SBAR();
  G2_LOADB(bv1, 32); SBAR();
  asm volatile("s_waitcnt vmcnt(8)" ::: "memory");
  G2_STAGEB(0, bv0);
  asm volatile("s_waitcnt lgkmcnt(0)" ::: "memory");
  __builtin_amdgcn_s_barrier();
  SBAR();

#define G2_BODY(T, ARD, AWR, BRD, BWR, RR, RW) do {                            \
    G2_LOADA(AWR, ((T) + 2) * 32);   SBAR();                                   \
    G2_LOADB(RW, ((T) + 2) * 32);    SBAR();                                   \
    G2_MFMA(ARD, BRD);                                                         \
    asm volatile("s_waitcnt vmcnt(10)" ::: "memory");                          \
    G2_STAGEB(BWR, RR);                                                        \
    asm volatile("s_waitcnt lgkmcnt(0)" ::: "memory");                         \
    __builtin_amdgcn_s_barrier();                                              \
    SBAR();                                                                    \
  } while (0)

  for (int t6 = 0; t6 < 30; t6 += 6) {
    G2_BODY(t6,     0, 2, 0, 1, bv1, bv0);
    G2_BODY(t6 + 1, 1, 0, 1, 0, bv0, bv1);
    G2_BODY(t6 + 2, 2, 1, 0, 1, bv1, bv0);
    G2_BODY(t6 + 3, 0, 2, 1, 0, bv0, bv1);
    G2_BODY(t6 + 4, 1, 0, 0, 1, bv1, bv0);
    G2_BODY(t6 + 5, 2, 1, 1, 0, bv0, bv1);
  }
  G2_MFMA(0, 0);
  asm volatile("s_waitcnt vmcnt(0)" ::: "memory");
  G2_STAGEB(1, bv1);
  asm volatile("s_waitcnt lgkmcnt(0)" ::: "memory");
  __builtin_amdgcn_s_barrier();
  SBAR();
  G2_MFMA(1, 1);
#undef G2_BODY
#undef G2_LOADA
#undef G2_LOADB
#undef G2_STAGEB
#undef G2_MFMA

  short* obase = yd + (size_t)(e * CAP + mt * 256) * DM + nt * 128;
UNROLL
  for (int m = 0; m < 4; ++m)
UNROLL
    for (int n = 0; n < 4; ++n)
UNROLL
      for (int j = 0; j < 4; ++j) {
        int rl = wm * 64 + m * 16 + (lane >> 4) * 4 + j;
        int cl = wn * 64 + n * 16 + (lane & 15);
        obase[(size_t)rl * DM + cl] = f2bf(acc[m][n][j]);
      }
}

// ---------------- combine: out[t] = sum_k w_k * yd[slot_k] ----------------
__global__ __launch_bounds__(256) void k_combine(const int* __restrict__ comb_slot,
                                                 const float* __restrict__ topw,
                                                 const short* __restrict__ yd,
                                                 float* __restrict__ out) {
  int t = blockIdx.x;
  int c = threadIdx.x * 4;
  f32x4 acc = (f32x4)0.f;
UNROLL
  for (int j = 0; j < 2; ++j) {
    int s = comb_slot[2 * t + j];
    if (s >= 0) {
      float w = topw[2 * t + j];
      short4v v = *(const short4v*)(yd + (size_t)s * DM + c);
UNROLL
      for (int q = 0; q < 4; ++q) acc[q] += w * bf2f(v[q]);
    }
  }
  *(f32x4*)(out + (size_t)t * DM + c) = acc;
}

extern "C" void kernel_launch(void* const* d_in, const int* in_sizes, int n_in,
                              void* d_out, int out_size, void* d_ws, size_t ws_size,
                              hipStream_t stream) {
  const float* hidden = (const float*)d_in[0];
  const int*   idx    = (const int*)d_in[1];
  const float* topw   = (const float*)d_in[2];
  const float* gup    = (const float*)d_in[3];
  const float* down   = (const float*)d_in[4];
  float* out = (float*)d_out;

  char* ws = (char*)d_ws;
  int*   slot_token = (int*)ws;                                   // 128KB
  int*   comb_slot  = (int*)(ws + 131072);                        // 64KB
  short* xd  = (short*)(ws + 131072 + 65536);                     // 64MB bf16
  short* act = xd + (size_t)NEXP * CAP * DM;                      // 64MB bf16
  short* yd  = act + (size_t)NEXP * CAP * DFF;                    // 64MB bf16

  k_route<<<NEXP, 256, 0, stream>>>(idx, slot_token, comb_slot);
  k_dispatch<<<NEXP * CAP, 256, 0, stream>>>(hidden, slot_token, xd);
  k_gemm1<<<2048, 512, 0, stream>>>(xd, gup, act);
  k_gemm2<<<1024, 512, 0, stream>>>(act, down, yd);
  k_combine<<<NTOK, 256, 0, stream>>>(comb_slot, topw, yd, out);
}